// Round 5
// baseline (1195.810 us; speedup 1.0000x reference)
//
#include <hip/hip_runtime.h>
#include <hip/hip_bf16.h>

typedef unsigned short u16;
typedef unsigned int u32;
typedef __attribute__((ext_vector_type(8))) short short8;
typedef __attribute__((ext_vector_type(4))) float f32x4;

#define NB 32      // trees
#define NN 128     // nodes per tree
#define HH 300     // hidden
#define G4 1200    // 4*H
#define NV 32000   // vocab
#define INW 350    // RD+E
#define KP 320     // padded K for MFMA (300 -> 320)

// scan decomposition
#define NSLICE 25  // 25 slices x 12 units
#define UPS 12     // hidden units per slice -> 48 gate rows
#define NREP 20    // replicas; queue pos p handled by replica p%NREP
#define TPB 192    // 48 rows x 4 col-chunks
#define GMAX 8     // max node batch
#define WI 88      // padded per-thread W count (75 -> 88, 176B, 16B aligned)
#define HP 320     // padded hidden for MV col space (4 chunks x 80)

#define A_LD(p)    __hip_atomic_load((p), __ATOMIC_RELAXED, __HIP_MEMORY_SCOPE_AGENT)
#define A_ST(p, v) __hip_atomic_store((p), (v), __ATOMIC_RELAXED, __HIP_MEMORY_SCOPE_AGENT)
#define A_ADD(p, v) __hip_atomic_fetch_add((p), (v), __ATOMIC_RELAXED, __HIP_MEMORY_SCOPE_AGENT)

__device__ __forceinline__ float sigm(float x) { return 1.f / (1.f + __expf(-x)); }
__device__ __forceinline__ float tanh_f(float x) {
    float e = __expf(2.f * x);
    return 1.f - 2.f / (e + 1.f);
}
__device__ __forceinline__ float bf2f(u16 v) {
    u32 u = ((u32)v) << 16;
    return __uint_as_float(u);
}

// h_buf/c_buf layout: [B][129][H]; slot 0 = root state
__global__ void k_init_roots(const float* __restrict__ rh, float* __restrict__ h_buf,
                             float* __restrict__ c_buf) {
    int n = blockIdx.x * blockDim.x + threadIdx.x;
    if (n < NB * HH) {
        int b = n / HH, u = n - b * HH;
        float v = rh[n];
        h_buf[(b * 129) * HH + u] = v;
        c_buf[(b * 129) * HH + u] = v;
    }
}

// WihT [350][1200] f32; Wpack16[slice][t<192][i<88] bf16:
//   rl=t%48, cc=t/48; row = 300*(rl/12) + 12*slice + rl%12; col = cc*80 + i
//   value = (i<80 && col<300) ? bf16(W_hh[row][col]) : 0
__global__ void k_pack(const float* __restrict__ W_ih, const float* __restrict__ W_hh,
                       float* __restrict__ WihT, u16* __restrict__ Wpack16) {
    const int tot = INW * G4 + NSLICE * TPB * WI;
    for (int n = blockIdx.x * blockDim.x + threadIdx.x; n < tot; n += gridDim.x * blockDim.x) {
        if (n < INW * G4) {
            int c = n / G4, r = n - c * G4;
            WihT[n] = W_ih[r * INW + c];
        } else {
            int m = n - INW * G4;
            int s = m / (TPB * WI);
            int rem = m - s * (TPB * WI);
            int t = rem / WI, i = rem - t * WI;
            int rl = t % 48, cc = t / 48;
            int row = 300 * (rl / UPS) + UPS * s + (rl % UPS);
            int col = cc * 80 + i;
            float v = (i < 80 && col < HH) ? W_hh[row * HH + col] : 0.f;
            __hip_bfloat16 b = __float2bfloat16(v);
            Wpack16[m] = *reinterpret_cast<u16*>(&b);
        }
    }
}

// xg[node][1200] = concat(rel_emb[rel], emb[word]) @ W_ih^T + b_ih
__global__ __launch_bounds__(256) void k_xg(const int* __restrict__ relations,
                                            const int* __restrict__ prev_words,
                                            const float* __restrict__ rel_emb,
                                            const float* __restrict__ emb,
                                            const float* __restrict__ WihT,
                                            const float* __restrict__ b_ih,
                                            float* __restrict__ xg) {
    __shared__ float xl[8][INW];
    __shared__ int rid[8], wid[8];
    const int tid = threadIdx.x;
    const int nb = blockIdx.x * 8;
    if (tid < 8) { rid[tid] = relations[nb + tid]; wid[tid] = prev_words[nb + tid]; }
    __syncthreads();
    for (int idx = tid; idx < 8 * INW; idx += 256) {
        int g = idx / INW, c = idx - g * INW;
        xl[g][c] = (c < 50) ? rel_emb[rid[g] * 50 + c] : emb[wid[g] * HH + (c - 50)];
    }
    __syncthreads();
    for (int k = 0; k < 5; ++k) {
        int r = k * 256 + tid;
        if (r >= G4) break;
        float acc[8] = {0.f, 0.f, 0.f, 0.f, 0.f, 0.f, 0.f, 0.f};
        for (int c = 0; c < INW; ++c) {
            float wv = WihT[(size_t)c * G4 + r];
#pragma unroll
            for (int g = 0; g < 8; ++g) acc[g] += wv * xl[g][c];
        }
        float bi = b_ih[r];
#pragma unroll
        for (int g = 0; g < 8; ++g) xg[(size_t)(nb + g) * G4 + r] = acc[g] + bi;
    }
}

// Build child adjacency, reset queue/done, enqueue roots. Deterministic per launch.
__global__ __launch_bounds__(1024) void k_prep(const int* __restrict__ parents,
                                               int* __restrict__ ready,
                                               int* __restrict__ qtail,
                                               int* __restrict__ kstart,
                                               int* __restrict__ kids,
                                               int* __restrict__ done) {
    __shared__ int cnt_s[4096];
    __shared__ int pfx_s[4096];
    __shared__ int part_s[64];
    __shared__ int rc_s;
    const int tid = threadIdx.x;
    for (int n = tid; n < NB * NN; n += 1024) { cnt_s[n] = 0; ready[n] = -1; done[n] = 0; }
    if (tid == 0) rc_s = 0;
    __syncthreads();
    for (int n = tid; n < NB * NN; n += 1024) {
        int p = parents[n];
        if (p >= 0) atomicAdd(&cnt_s[(n & ~127) + p], 1);
    }
    __syncthreads();
    if (tid < 64) {
        int s = 0;
        for (int k = 0; k < 64; ++k) { int t = cnt_s[tid * 64 + k]; pfx_s[tid * 64 + k] = s; s += t; }
        part_s[tid] = s;
    }
    __syncthreads();
    if (tid == 0) {
        int s = 0;
        for (int k = 0; k < 64; ++k) { int t = part_s[k]; part_s[k] = s; s += t; }
        kstart[4096] = s;
    }
    __syncthreads();
    if (tid < 64) {
        int off = part_s[tid];
        for (int k = 0; k < 64; ++k) pfx_s[tid * 64 + k] += off;
    }
    __syncthreads();
    for (int n = tid; n < NB * NN; n += 1024) kstart[n] = pfx_s[n];
    __syncthreads();
    for (int n = tid; n < NB * NN; n += 1024) {
        int p = parents[n];
        if (p >= 0) {
            int pos = atomicAdd(&pfx_s[(n & ~127) + p], 1);
            kids[pos] = n;
        } else {
            int slot = atomicAdd(&rc_s, 1);
            ready[slot] = n;
        }
    }
    __syncthreads();
    if (tid == 0) qtail[0] = rc_s;
}

// MV + cell for one batch of G nodes, one 12-unit slice. W slice in LDS (bf16).
template <int G>
__device__ __forceinline__ void mv_cell(const u16* __restrict__ wl, int t, int rl, int cc,
                                        int slice,
                                        const int* __restrict__ nid_s,
                                        const float* __restrict__ xg,
                                        const float* __restrict__ b_hh,
                                        float* __restrict__ h_buf,
                                        float* __restrict__ c_buf,
                                        const float* __restrict__ ph,
                                        float* __restrict__ pr,
                                        const float* __restrict__ pcl) {
    float acc[G];
#pragma unroll
    for (int j = 0; j < G; ++j) acc[j] = 0.f;
    const u16* wrow = wl + t * WI;
    const int cbase = cc * 80;
#pragma unroll
    for (int ch = 0; ch < 10; ++ch) {
        short8 wv8 = *(const short8*)&wrow[ch * 8];
#pragma unroll
        for (int e = 0; e < 8; ++e) {
            const float wv = bf2f((u16)wv8[e]);
            const int c = cbase + ch * 8 + e;
            if constexpr (G == 8) {
                f32x4 a = *(const f32x4*)&ph[c * GMAX];
                f32x4 b = *(const f32x4*)&ph[c * GMAX + 4];
                acc[0] = fmaf(wv, a[0], acc[0]); acc[1] = fmaf(wv, a[1], acc[1]);
                acc[2] = fmaf(wv, a[2], acc[2]); acc[3] = fmaf(wv, a[3], acc[3]);
                acc[4] = fmaf(wv, b[0], acc[4]); acc[5] = fmaf(wv, b[1], acc[5]);
                acc[6] = fmaf(wv, b[2], acc[6]); acc[7] = fmaf(wv, b[3], acc[7]);
            } else if constexpr (G == 4) {
                f32x4 a = *(const f32x4*)&ph[c * GMAX];
                acc[0] = fmaf(wv, a[0], acc[0]); acc[1] = fmaf(wv, a[1], acc[1]);
                acc[2] = fmaf(wv, a[2], acc[2]); acc[3] = fmaf(wv, a[3], acc[3]);
            } else {
#pragma unroll
                for (int j = 0; j < G; ++j) acc[j] = fmaf(wv, ph[c * GMAX + j], acc[j]);
            }
        }
    }
    // partials -> LDS
#pragma unroll
    for (int j = 0; j < G; ++j) pr[(cc * 48 + rl) * GMAX + j] = acc[j];
    __syncthreads();
    // cell: thread t < 12*G handles (unit ul, node j)
    if (t < UPS * G) {
        const int ul = t % UPS, j = t / UPS;
        const int n = nid_s[j];
        const int u = slice * UPS + ul;
        float gs[4];
#pragma unroll
        for (int g = 0; g < 4; ++g) {
            const int rr = g * UPS + ul;
            float sum = pr[(0 * 48 + rr) * GMAX + j] + pr[(1 * 48 + rr) * GMAX + j] +
                        pr[(2 * 48 + rr) * GMAX + j] + pr[(3 * 48 + rr) * GMAX + j];
            gs[g] = sum + xg[(size_t)n * G4 + g * HH + u] + b_hh[g * HH + u];
        }
        const float pc = pcl[t];
        const float cv = sigm(gs[1]) * pc + sigm(gs[0]) * tanh_f(gs[2]);
        const float hv = sigm(gs[3]) * tanh_f(cv);
        const size_t o = (size_t)((n >> 7) * 129 + (n & 127) + 1) * HH + u;
        c_buf[o] = cv;
        h_buf[o] = hv;
    }
}

// Dataflow scan: 25 slices x 20 replicas = 500 blocks, NORMAL launch.
// Co-residency by construction: LDS ~50.6KB -> 3 blocks/CU (worst case 2) -> >=512
// co-resident blocks on 256 CUs; no grid.sync used, only poll + fences.
// Coherence (R2-proven): plain h/c stores; producer tid0 __threadfence() after
// barrier, before done[] add; consumer tid0 __threadfence() after poll success.
__global__ __launch_bounds__(TPB, 3) void k_scan_slice(const int* __restrict__ parents,
                                                       const u16* __restrict__ Wpack16,
                                                       const float* __restrict__ xg,
                                                       const float* __restrict__ b_hh,
                                                       float* __restrict__ h_buf,
                                                       float* __restrict__ c_buf,
                                                       int* __restrict__ ready,
                                                       int* __restrict__ qtail,
                                                       int* __restrict__ done,
                                                       const int* __restrict__ kstart,
                                                       const int* __restrict__ kids) {
    __shared__ __align__(16) u16 wl[TPB * WI];   // 33792 B, W slice (bf16)
    __shared__ float ph[HP * GMAX];              // 10240 B, parent h (padded), [c][j]
    __shared__ float pcl[UPS * GMAX];            // 384 B, parent c slice
    __shared__ float pr[4 * 48 * GMAX];          // 6144 B, MV partials
    __shared__ int nid_s[GMAX];
    __shared__ int par_s[GMAX];
    __shared__ int gc_s;

    const int t = threadIdx.x;
    const int rep = blockIdx.x % NREP;
    const int slice = blockIdx.x / NREP;
    const int rl = t % 48, cc = t / 48;

    // stage W slice into LDS once (coalesced uint4 copy: 2112 uint4 = 11/thread)
    {
        const uint4* src = (const uint4*)(Wpack16 + (size_t)slice * TPB * WI);
        uint4* dst = (uint4*)wl;
#pragma unroll
        for (int q = 0; q < 11; ++q) dst[q * TPB + t] = src[q * TPB + t];
    }
    __syncthreads();

    const int cnt = (4095 - rep) / NREP + 1;  // my queue positions: rep + k*NREP
    int got = 0;
    while (got < cnt) {
        if (t == 0) {
            int v;
            while ((v = A_LD(&ready[rep + got * NREP])) < 0) __builtin_amdgcn_s_sleep(4);
            nid_s[0] = v; par_s[0] = parents[v];
            int avail = 1;
            while (avail < GMAX && got + avail < cnt) {
                int u = A_LD(&ready[rep + (got + avail) * NREP]);
                if (u < 0) break;
                nid_s[avail] = u; par_s[avail] = parents[u];
                ++avail;
            }
            gc_s = (avail >= 8) ? 8 : (avail >= 4) ? 4 : (avail >= 2) ? 2 : 1;
            __threadfence();  // acquire: drop stale cached h/c before block reads
        }
        __syncthreads();
        const int gc = gc_s;
        // stage parent h into LDS [c][j], zero-padded cols 300..319
        for (int e = t; e < HP * gc; e += TPB) {
            const int j = e / HP, c = e - j * HP;
            const int n = nid_s[j];
            ph[c * GMAX + j] =
                (c < HH) ? h_buf[(size_t)((n >> 7) * 129 + par_s[j] + 1) * HH + c] : 0.f;
        }
        // stage parent c slice
        for (int e = t; e < UPS * gc; e += TPB) {
            const int j = e / UPS, ul = e - j * UPS;
            const int n = nid_s[j];
            pcl[e] = c_buf[(size_t)((n >> 7) * 129 + par_s[j] + 1) * HH + slice * UPS + ul];
        }
        __syncthreads();
        switch (gc) {
            case 8: mv_cell<8>(wl, t, rl, cc, slice, nid_s, xg, b_hh, h_buf, c_buf, ph, pr, pcl); break;
            case 4: mv_cell<4>(wl, t, rl, cc, slice, nid_s, xg, b_hh, h_buf, c_buf, ph, pr, pcl); break;
            case 2: mv_cell<2>(wl, t, rl, cc, slice, nid_s, xg, b_hh, h_buf, c_buf, ph, pr, pcl); break;
            default: mv_cell<1>(wl, t, rl, cc, slice, nid_s, xg, b_hh, h_buf, c_buf, ph, pr, pcl); break;
        }
        const int n_mine = (t < gc) ? nid_s[t] : -1;
        // barrier drains every thread's h/c stores (vmcnt) before the release fence
        __syncthreads();
        if (t == 0) __threadfence();  // release: write back dirty L2 so h/c reach MALL
        __syncthreads();              // no done[] add until the fence is complete
        if (t < gc) {
            const int old = A_ADD(&done[n_mine], 1);
            if (old == NSLICE - 1) {  // all 25 slices done -> children ready
                const int ks = kstart[n_mine], ke = kstart[n_mine + 1];
                for (int q = ks; q < ke; ++q) {
                    const int kd = kids[q];
                    const int pos = A_ADD(qtail, 1);
                    A_ST(&ready[pos], kd);
                }
            }
        }
        got += gc;
    }
}

// cast hs -> bf16 [4096][320] (zero-padded K), W_out -> bf16 [32000][320]
__global__ void k_cast_A(const float* __restrict__ h_buf, u16* __restrict__ A) {
    for (int e = blockIdx.x * blockDim.x + threadIdx.x; e < NB * NN * KP;
         e += gridDim.x * blockDim.x) {
        int n = e / KP, k = e - n * KP;
        float v = 0.f;
        if (k < HH) v = h_buf[((n >> 7) * 129 + (n & 127) + 1) * HH + k];
        __hip_bfloat16 b = __float2bfloat16(v);
        A[e] = *reinterpret_cast<u16*>(&b);
    }
}

__global__ void k_cast_B(const float* __restrict__ W_out, u16* __restrict__ Bm) {
    for (int e = blockIdx.x * blockDim.x + threadIdx.x; e < NV * KP;
         e += gridDim.x * blockDim.x) {
        int v = e / KP, k = e - v * KP;
        float x = (k < HH) ? W_out[v * HH + k] : 0.f;
        __hip_bfloat16 b = __float2bfloat16(x);
        Bm[e] = *reinterpret_cast<u16*>(&b);
    }
}

// logits[4096][32000] = A(bf16) @ B(bf16)^T + b_out, fp32 accum.
__global__ __launch_bounds__(256) void k_gemm(const u16* __restrict__ Abf,
                                              const u16* __restrict__ Bbf,
                                              const float* __restrict__ b_out,
                                              float* __restrict__ out) {
    __shared__ __align__(16) u16 As[128 * 40];
    __shared__ __align__(16) u16 Bs[128 * 40];
    const int tid = threadIdx.x;
    const int lane = tid & 63, wv = tid >> 6;
    const int wm = wv >> 1, wn = wv & 1;
    const int mblk = blockIdx.x, nblk = blockIdx.y;
    const u16* Ag = Abf + (size_t)mblk * 128 * KP;
    const u16* Bg = Bbf + (size_t)nblk * 128 * KP;
    f32x4 acc[4][4] = {};
    const int lrow = lane & 15, lseg = lane >> 4;
    for (int kk = 0; kk < KP; kk += 32) {
#pragma unroll
        for (int q = 0; q < 2; ++q) {
            int s = tid + q * 256;
            int r = s >> 2, seg = s & 3;
            *(uint4*)&As[r * 40 + seg * 8] = *(const uint4*)&Ag[r * KP + kk + seg * 8];
            *(uint4*)&Bs[r * 40 + seg * 8] = *(const uint4*)&Bg[r * KP + kk + seg * 8];
        }
        __syncthreads();
        short8 av[4], bv[4];
#pragma unroll
        for (int i = 0; i < 4; ++i) {
            av[i] = *(const short8*)&As[(wm * 64 + i * 16 + lrow) * 40 + lseg * 8];
            bv[i] = *(const short8*)&Bs[(wn * 64 + i * 16 + lrow) * 40 + lseg * 8];
        }
#pragma unroll
        for (int i = 0; i < 4; ++i)
#pragma unroll
            for (int j = 0; j < 4; ++j)
                acc[i][j] = __builtin_amdgcn_mfma_f32_16x16x32_bf16(av[i], bv[j], acc[i][j],
                                                                    0, 0, 0);
        __syncthreads();
    }
#pragma unroll
    for (int j = 0; j < 4; ++j) {
        int col = nblk * 128 + wn * 64 + j * 16 + lrow;
        float bo = b_out[col];
#pragma unroll
        for (int i = 0; i < 4; ++i) {
            int row0 = mblk * 128 + wm * 64 + i * 16 + lseg * 4;
#pragma unroll
            for (int q = 0; q < 4; ++q) {
                out[(size_t)(row0 + q) * NV + col] = acc[i][j][q] + bo;
            }
        }
    }
}

extern "C" void kernel_launch(void* const* d_in, const int* in_sizes, int n_in,
                              void* d_out, int out_size, void* d_ws, size_t ws_size,
                              hipStream_t stream) {
    const float* root_hidden = (const float*)d_in[0];
    const int* relations = (const int*)d_in[1];
    const int* prev_words = (const int*)d_in[2];
    const int* parents = (const int*)d_in[3];
    const float* emb = (const float*)d_in[4];
    const float* rel_emb = (const float*)d_in[5];
    const float* W_ih = (const float*)d_in[6];
    const float* W_hh = (const float*)d_in[7];
    const float* b_ih = (const float*)d_in[8];
    const float* b_hh = (const float*)d_in[9];
    const float* W_out = (const float*)d_in[10];
    const float* b_out = (const float*)d_in[11];
    float* out = (float*)d_out;

    float* WihT = (float*)d_ws;                  // 420000 f32
    u16* Wpack16 = (u16*)(WihT + 420000);        // 422400 u16 (16B-aligned)
    float* xg = (float*)(Wpack16 + 422400);      // 4915200 f32
    float* h_buf = xg + 4915200;                 // 1238400 f32
    float* c_buf = h_buf + 1238400;              // 1238400 f32
    u16* Abf = (u16*)(c_buf + 1238400);          // 1310720 u16
    u16* Bbf = Abf + 1310720;                    // 10240000 u16
    int* ready = (int*)(Bbf + 10240000);         // 4096 i32
    int* qtail = ready + 4096;                   // 16 i32
    int* kstart = qtail + 16;                    // 4097 i32
    int* kids = kstart + 4097;                   // 4096 i32 (+pad)
    int* done = kids + 4112;                     // 4096 i32

    k_init_roots<<<(NB * HH + 255) / 256, 256, 0, stream>>>(root_hidden, h_buf, c_buf);
    k_pack<<<2048, 256, 0, stream>>>(W_ih, W_hh, WihT, Wpack16);
    k_xg<<<NB * NN / 8, 256, 0, stream>>>(relations, prev_words, rel_emb, emb, WihT, b_ih, xg);
    k_prep<<<1, 1024, 0, stream>>>(parents, ready, qtail, kstart, kids, done);

    k_scan_slice<<<dim3(NSLICE * NREP), dim3(TPB), 0, stream>>>(
        parents, Wpack16, xg, b_hh, h_buf, c_buf, ready, qtail, done, kstart, kids);

    k_cast_A<<<2048, 256, 0, stream>>>(h_buf, Abf);
    k_cast_B<<<4096, 256, 0, stream>>>(W_out, Bbf);
    k_gemm<<<dim3(NB * NN / 128, NV / 128), 256, 0, stream>>>(Abf, Bbf, b_out, out);
}

// Round 6
// 818.205 us; speedup vs baseline: 1.4615x; 1.4615x over previous
//
#include <hip/hip_runtime.h>
#include <hip/hip_bf16.h>

typedef unsigned short u16;
typedef unsigned int u32;
typedef __attribute__((ext_vector_type(8))) short short8;
typedef __attribute__((ext_vector_type(4))) float f32x4;

#define NB 32      // trees
#define NN 128     // nodes per tree
#define HH 300     // hidden
#define G4 1200    // 4*H
#define NV 32000   // vocab
#define INW 350    // RD+E
#define KP 320     // padded K for MFMA (300 -> 320)

// scan decomposition
#define NSLICE 25  // 25 slices x 12 units
#define UPS 12     // hidden units per slice -> 48 gate rows
#define NREP 20    // replicas; chunk q owned by replica q%NREP
#define TPB 192    // 48 rows x 4 col-chunks
#define GMAX 16    // chunk size / max node batch
#define NCHUNK 256 // 4096/16

#define A_LD(p)    __hip_atomic_load((p), __ATOMIC_RELAXED, __HIP_MEMORY_SCOPE_AGENT)
#define A_ST(p, v) __hip_atomic_store((p), (v), __ATOMIC_RELAXED, __HIP_MEMORY_SCOPE_AGENT)
#define A_ADD(p, v) __hip_atomic_fetch_add((p), (v), __ATOMIC_RELAXED, __HIP_MEMORY_SCOPE_AGENT)

__device__ __forceinline__ float sigm(float x) { return 1.f / (1.f + __expf(-x)); }
__device__ __forceinline__ float tanh_f(float x) {
    float e = __expf(2.f * x);
    return 1.f - 2.f / (e + 1.f);
}

// h_buf/c_buf layout: [B][129][H]; slot 0 = root state
__global__ void k_init_roots(const float* __restrict__ rh, float* __restrict__ h_buf,
                             float* __restrict__ c_buf) {
    int n = blockIdx.x * blockDim.x + threadIdx.x;
    if (n < NB * HH) {
        int b = n / HH, u = n - b * HH;
        float v = rh[n];
        h_buf[(b * 129) * HH + u] = v;
        c_buf[(b * 129) * HH + u] = v;
    }
}

// WihT [350][1200]; Wpack[slice][i<75][t<192] = W_hh[row(slice,t)][(t/48)*75+i]
// row(s,t) = 300*(rl/12) + 12*s + rl%12, rl = t%48
__global__ void k_pack(const float* __restrict__ W_ih, const float* __restrict__ W_hh,
                       float* __restrict__ WihT, float* __restrict__ Wpack) {
    const int tot = INW * G4 + NSLICE * 75 * TPB;
    for (int n = blockIdx.x * blockDim.x + threadIdx.x; n < tot; n += gridDim.x * blockDim.x) {
        if (n < INW * G4) {
            int c = n / G4, r = n - c * G4;
            WihT[n] = W_ih[r * INW + c];
        } else {
            int m = n - INW * G4;
            int s = m / (75 * TPB);
            int rem = m - s * (75 * TPB);
            int i = rem / TPB, t = rem - i * TPB;
            int rl = t % 48, cc = t / 48;
            int row = 300 * (rl / UPS) + UPS * s + (rl % UPS);
            int col = cc * 75 + i;
            Wpack[m] = W_hh[row * HH + col];
        }
    }
}

// xg[node][1200] = concat(rel_emb[rel], emb[word]) @ W_ih^T + b_ih
__global__ __launch_bounds__(256) void k_xg(const int* __restrict__ relations,
                                            const int* __restrict__ prev_words,
                                            const float* __restrict__ rel_emb,
                                            const float* __restrict__ emb,
                                            const float* __restrict__ WihT,
                                            const float* __restrict__ b_ih,
                                            float* __restrict__ xg) {
    __shared__ float xl[8][INW];
    __shared__ int rid[8], wid[8];
    const int tid = threadIdx.x;
    const int nb = blockIdx.x * 8;
    if (tid < 8) { rid[tid] = relations[nb + tid]; wid[tid] = prev_words[nb + tid]; }
    __syncthreads();
    for (int idx = tid; idx < 8 * INW; idx += 256) {
        int g = idx / INW, c = idx - g * INW;
        xl[g][c] = (c < 50) ? rel_emb[rid[g] * 50 + c] : emb[wid[g] * HH + (c - 50)];
    }
    __syncthreads();
    for (int k = 0; k < 5; ++k) {
        int r = k * 256 + tid;
        if (r >= G4) break;
        float acc[8] = {0.f, 0.f, 0.f, 0.f, 0.f, 0.f, 0.f, 0.f};
        for (int c = 0; c < INW; ++c) {
            float wv = WihT[(size_t)c * G4 + r];
#pragma unroll
            for (int g = 0; g < 8; ++g) acc[g] += wv * xl[g][c];
        }
        float bi = b_ih[r];
#pragma unroll
        for (int g = 0; g < 8; ++g) xg[(size_t)(nb + g) * G4 + r] = acc[g] + bi;
    }
}

// Build child adjacency, reset queue/done, enqueue roots. Deterministic per launch.
__global__ __launch_bounds__(1024) void k_prep(const int* __restrict__ parents,
                                               int* __restrict__ ready,
                                               int* __restrict__ qtail,
                                               int* __restrict__ kstart,
                                               int* __restrict__ kids,
                                               int* __restrict__ done) {
    __shared__ int cnt_s[4096];
    __shared__ int pfx_s[4096];
    __shared__ int part_s[64];
    __shared__ int rc_s;
    const int tid = threadIdx.x;
    for (int n = tid; n < NB * NN; n += 1024) { cnt_s[n] = 0; ready[n] = -1; done[n] = 0; }
    if (tid == 0) rc_s = 0;
    __syncthreads();
    for (int n = tid; n < NB * NN; n += 1024) {
        int p = parents[n];
        if (p >= 0) atomicAdd(&cnt_s[(n & ~127) + p], 1);
    }
    __syncthreads();
    if (tid < 64) {
        int s = 0;
        for (int k = 0; k < 64; ++k) { int t = cnt_s[tid * 64 + k]; pfx_s[tid * 64 + k] = s; s += t; }
        part_s[tid] = s;
    }
    __syncthreads();
    if (tid == 0) {
        int s = 0;
        for (int k = 0; k < 64; ++k) { int t = part_s[k]; part_s[k] = s; s += t; }
        kstart[4096] = s;
    }
    __syncthreads();
    if (tid < 64) {
        int off = part_s[tid];
        for (int k = 0; k < 64; ++k) pfx_s[tid * 64 + k] += off;
    }
    __syncthreads();
    for (int n = tid; n < NB * NN; n += 1024) kstart[n] = pfx_s[n];
    __syncthreads();
    for (int n = tid; n < NB * NN; n += 1024) {
        int p = parents[n];
        if (p >= 0) {
            int pos = atomicAdd(&pfx_s[(n & ~127) + p], 1);
            kids[pos] = n;
        } else {
            int slot = atomicAdd(&rc_s, 1);
            ready[slot] = n;
        }
    }
    __syncthreads();
    if (tid == 0) qtail[0] = rc_s;
}

// MV + cell for one batch of G nodes, one 12-unit slice. W in VGPRs; ph broadcast
// reads from LDS (conflict-free); pr stored [j][192] (conflict-free scalar).
template <int G>
__device__ __forceinline__ void mv_cell(const float (&w)[75], int t, int rl, int cc, int slice,
                                        const int* __restrict__ nid_s,
                                        const float* __restrict__ xg,
                                        const float* __restrict__ b_hh,
                                        float* __restrict__ h_buf,
                                        float* __restrict__ c_buf,
                                        const float* __restrict__ ph,
                                        float* __restrict__ pr,
                                        const float* __restrict__ pcl) {
    float acc[G];
#pragma unroll
    for (int j = 0; j < G; ++j) acc[j] = 0.f;
    const int cb = cc * 75;
#pragma unroll 5
    for (int i = 0; i < 75; ++i) {
        const float wv = w[i];
        const float* pp = &ph[(cb + i) * GMAX];
        if constexpr (G >= 4) {
#pragma unroll
            for (int j4 = 0; j4 < G; j4 += 4) {
                f32x4 a = *(const f32x4*)&pp[j4];
                acc[j4 + 0] = fmaf(wv, a[0], acc[j4 + 0]);
                acc[j4 + 1] = fmaf(wv, a[1], acc[j4 + 1]);
                acc[j4 + 2] = fmaf(wv, a[2], acc[j4 + 2]);
                acc[j4 + 3] = fmaf(wv, a[3], acc[j4 + 3]);
            }
        } else {
#pragma unroll
            for (int j = 0; j < G; ++j) acc[j] = fmaf(wv, pp[j], acc[j]);
        }
    }
    // partials: pr[j][cc*48+rl]
#pragma unroll
    for (int j = 0; j < G; ++j) pr[j * TPB + cc * 48 + rl] = acc[j];
    __syncthreads();
    // cell: thread t < 12*G handles (node j, unit ul)
    if (t < UPS * G) {
        const int ul = t % UPS, j = t / UPS;
        const int n = nid_s[j];
        const int u = slice * UPS + ul;
        float gs[4];
#pragma unroll
        for (int g = 0; g < 4; ++g) {
            const int rr = g * UPS + ul;
            const float* pj = pr + j * TPB;
            float sum = pj[rr] + pj[48 + rr] + pj[96 + rr] + pj[144 + rr];
            gs[g] = sum + xg[(size_t)n * G4 + g * HH + u] + b_hh[g * HH + u];
        }
        const float pc = pcl[t];
        const float cv = sigm(gs[1]) * pc + sigm(gs[0]) * tanh_f(gs[2]);
        const float hv = sigm(gs[3]) * tanh_f(cv);
        const size_t o = (size_t)((n >> 7) * 129 + (n & 127) + 1) * HH + u;
        A_ST(&c_buf[o], cv);
        A_ST(&h_buf[o], hv);
    }
}

// Dataflow scan: 25 slices x 20 replicas = 500 blocks, normal launch.
// Ownership block-cyclic by 16-position chunks: chunk q owned by rep q%NREP.
// All h/c traffic via relaxed agent-scope atomics (sc1, coherent at MALL) -> no
// fences. Producer order: __syncthreads (vmcnt0 drain) before done[] add;
// 25th done-add publishes children to ready[].
__global__ __launch_bounds__(TPB, 2) void k_scan_slice(const int* __restrict__ parents,
                                                       const float* __restrict__ Wpack,
                                                       const float* __restrict__ xg,
                                                       const float* __restrict__ b_hh,
                                                       float* __restrict__ h_buf,
                                                       float* __restrict__ c_buf,
                                                       int* __restrict__ ready,
                                                       int* __restrict__ qtail,
                                                       int* __restrict__ done,
                                                       const int* __restrict__ kstart,
                                                       const int* __restrict__ kids) {
    __shared__ __align__(16) float ph[HH * GMAX];   // 19.2 KB parent h, [c][j]
    __shared__ float pr[GMAX * TPB];                // 12.3 KB MV partials, [j][cc*48+rl]
    __shared__ float pcl[UPS * GMAX];               // parent c slice, [j*12+ul]
    __shared__ int nid_s[GMAX];
    __shared__ int par_s[GMAX];
    __shared__ int gc_s;

    const int t = threadIdx.x;
    const int rep = blockIdx.x % NREP;
    const int slice = blockIdx.x / NREP;
    const int rl = t % 48, cc = t / 48;

    // register-resident W slice (once per block, coalesced)
    float w[75];
    {
        const float* wp = Wpack + (size_t)slice * 75 * TPB + t;
#pragma unroll
        for (int i = 0; i < 75; ++i) w[i] = wp[i * TPB];
    }

    for (int ch = rep; ch < NCHUNK; ch += NREP) {
        const int base = ch * GMAX;
        int lp = 0;
        while (lp < GMAX) {
            if (t == 0) {
                int v;
                while ((v = A_LD(&ready[base + lp])) < 0) __builtin_amdgcn_s_sleep(2);
                nid_s[0] = v; par_s[0] = parents[v];
                int avail = 1;
                while (lp + avail < GMAX) {
                    int u = A_LD(&ready[base + lp + avail]);
                    if (u < 0) break;
                    nid_s[avail] = u; par_s[avail] = parents[u];
                    ++avail;
                }
                gc_s = (avail >= 16) ? 16 : (avail >= 8) ? 8 : (avail >= 4) ? 4
                                                        : (avail >= 2) ? 2 : 1;
            }
            __syncthreads();
            const int gc = gc_s;
            const int lg = (gc == 16) ? 4 : (gc == 8) ? 3 : (gc == 4) ? 2 : (gc == 2) ? 1 : 0;
            // stage parent h into LDS [c][j] via coherent atomic loads
            for (int e = t; e < HH * gc; e += TPB) {
                const int j = e & (gc - 1), c = e >> lg;
                const int n = nid_s[j];
                ph[c * GMAX + j] =
                    A_LD(&h_buf[(size_t)((n >> 7) * 129 + par_s[j] + 1) * HH + c]);
            }
            // stage parent c slice
            for (int e = t; e < UPS * gc; e += TPB) {
                const int j = e / UPS, ul = e - j * UPS;
                const int n = nid_s[j];
                pcl[e] = A_LD(&c_buf[(size_t)((n >> 7) * 129 + par_s[j] + 1) * HH +
                                     slice * UPS + ul]);
            }
            __syncthreads();
            switch (gc) {
                case 16: mv_cell<16>(w, t, rl, cc, slice, nid_s, xg, b_hh, h_buf, c_buf, ph, pr, pcl); break;
                case 8:  mv_cell<8>(w, t, rl, cc, slice, nid_s, xg, b_hh, h_buf, c_buf, ph, pr, pcl); break;
                case 4:  mv_cell<4>(w, t, rl, cc, slice, nid_s, xg, b_hh, h_buf, c_buf, ph, pr, pcl); break;
                case 2:  mv_cell<2>(w, t, rl, cc, slice, nid_s, xg, b_hh, h_buf, c_buf, ph, pr, pcl); break;
                default: mv_cell<1>(w, t, rl, cc, slice, nid_s, xg, b_hh, h_buf, c_buf, ph, pr, pcl); break;
            }
            // barrier drains all threads' h/c atomic stores (vmcnt0) before done adds
            __syncthreads();
            if (t < gc) {
                const int n_mine = nid_s[t];
                const int old = A_ADD(&done[n_mine], 1);
                if (old == NSLICE - 1) {  // all 25 slices done -> children ready
                    const int ks = kstart[n_mine], ke = kstart[n_mine + 1];
                    for (int q = ks; q < ke; ++q) {
                        const int kd = kids[q];
                        const int pos = A_ADD(qtail, 1);
                        A_ST(&ready[pos], kd);
                    }
                }
            }
            lp += gc;
            __syncthreads();  // nid_s reuse safety for next poll
        }
    }
}

// cast hs -> bf16 [4096][320] (zero-padded K), W_out -> bf16 [32000][320]
__global__ void k_cast_A(const float* __restrict__ h_buf, u16* __restrict__ A) {
    for (int e = blockIdx.x * blockDim.x + threadIdx.x; e < NB * NN * KP;
         e += gridDim.x * blockDim.x) {
        int n = e / KP, k = e - n * KP;
        float v = 0.f;
        if (k < HH) v = h_buf[((n >> 7) * 129 + (n & 127) + 1) * HH + k];
        __hip_bfloat16 b = __float2bfloat16(v);
        A[e] = *reinterpret_cast<u16*>(&b);
    }
}

__global__ void k_cast_B(const float* __restrict__ W_out, u16* __restrict__ Bm) {
    for (int e = blockIdx.x * blockDim.x + threadIdx.x; e < NV * KP;
         e += gridDim.x * blockDim.x) {
        int v = e / KP, k = e - v * KP;
        float x = (k < HH) ? W_out[v * HH + k] : 0.f;
        __hip_bfloat16 b = __float2bfloat16(x);
        Bm[e] = *reinterpret_cast<u16*>(&b);
    }
}

// logits[4096][32000] = A(bf16) @ B(bf16)^T + b_out, fp32 accum.
__global__ __launch_bounds__(256) void k_gemm(const u16* __restrict__ Abf,
                                              const u16* __restrict__ Bbf,
                                              const float* __restrict__ b_out,
                                              float* __restrict__ out) {
    __shared__ __align__(16) u16 As[128 * 40];
    __shared__ __align__(16) u16 Bs[128 * 40];
    const int tid = threadIdx.x;
    const int lane = tid & 63, wv = tid >> 6;
    const int wm = wv >> 1, wn = wv & 1;
    const int mblk = blockIdx.x, nblk = blockIdx.y;
    const u16* Ag = Abf + (size_t)mblk * 128 * KP;
    const u16* Bg = Bbf + (size_t)nblk * 128 * KP;
    f32x4 acc[4][4] = {};
    const int lrow = lane & 15, lseg = lane >> 4;
    for (int kk = 0; kk < KP; kk += 32) {
#pragma unroll
        for (int q = 0; q < 2; ++q) {
            int s = tid + q * 256;
            int r = s >> 2, seg = s & 3;
            *(uint4*)&As[r * 40 + seg * 8] = *(const uint4*)&Ag[r * KP + kk + seg * 8];
            *(uint4*)&Bs[r * 40 + seg * 8] = *(const uint4*)&Bg[r * KP + kk + seg * 8];
        }
        __syncthreads();
        short8 av[4], bv[4];
#pragma unroll
        for (int i = 0; i < 4; ++i) {
            av[i] = *(const short8*)&As[(wm * 64 + i * 16 + lrow) * 40 + lseg * 8];
            bv[i] = *(const short8*)&Bs[(wn * 64 + i * 16 + lrow) * 40 + lseg * 8];
        }
#pragma unroll
        for (int i = 0; i < 4; ++i)
#pragma unroll
            for (int j = 0; j < 4; ++j)
                acc[i][j] = __builtin_amdgcn_mfma_f32_16x16x32_bf16(av[i], bv[j], acc[i][j],
                                                                    0, 0, 0);
        __syncthreads();
    }
#pragma unroll
    for (int j = 0; j < 4; ++j) {
        int col = nblk * 128 + wn * 64 + j * 16 + lrow;
        float bo = b_out[col];
#pragma unroll
        for (int i = 0; i < 4; ++i) {
            int row0 = mblk * 128 + wm * 64 + i * 16 + lseg * 4;
#pragma unroll
            for (int q = 0; q < 4; ++q) {
                out[(size_t)(row0 + q) * NV + col] = acc[i][j][q] + bo;
            }
        }
    }
}

extern "C" void kernel_launch(void* const* d_in, const int* in_sizes, int n_in,
                              void* d_out, int out_size, void* d_ws, size_t ws_size,
                              hipStream_t stream) {
    const float* root_hidden = (const float*)d_in[0];
    const int* relations = (const int*)d_in[1];
    const int* prev_words = (const int*)d_in[2];
    const int* parents = (const int*)d_in[3];
    const float* emb = (const float*)d_in[4];
    const float* rel_emb = (const float*)d_in[5];
    const float* W_ih = (const float*)d_in[6];
    const float* W_hh = (const float*)d_in[7];
    const float* b_ih = (const float*)d_in[8];
    const float* b_hh = (const float*)d_in[9];
    const float* W_out = (const float*)d_in[10];
    const float* b_out = (const float*)d_in[11];
    float* out = (float*)d_out;

    float* WihT = (float*)d_ws;                  // 420000 f32
    float* Wpack = WihT + 420000;                // 360000 f32
    float* xg = Wpack + 360000;                  // 4915200 f32
    float* h_buf = xg + 4915200;                 // 1238400 f32
    float* c_buf = h_buf + 1238400;              // 1238400 f32
    u16* Abf = (u16*)(c_buf + 1238400);          // 1310720 u16
    u16* Bbf = Abf + 1310720;                    // 10240000 u16
    int* ready = (int*)(Bbf + 10240000);         // 4096 i32
    int* qtail = ready + 4096;                   // 16 i32
    int* kstart = qtail + 16;                    // 4097 i32
    int* kids = kstart + 4097;                   // 4096 i32 (+pad)
    int* done = kids + 4112;                     // 4096 i32

    k_init_roots<<<(NB * HH + 255) / 256, 256, 0, stream>>>(root_hidden, h_buf, c_buf);
    k_pack<<<2048, 256, 0, stream>>>(W_ih, W_hh, WihT, Wpack);
    k_xg<<<NB * NN / 8, 256, 0, stream>>>(relations, prev_words, rel_emb, emb, WihT, b_ih, xg);
    k_prep<<<1, 1024, 0, stream>>>(parents, ready, qtail, kstart, kids, done);

    k_scan_slice<<<dim3(NSLICE * NREP), dim3(TPB), 0, stream>>>(
        parents, Wpack, xg, b_hh, h_buf, c_buf, ready, qtail, done, kstart, kids);

    k_cast_A<<<2048, 256, 0, stream>>>(h_buf, Abf);
    k_cast_B<<<4096, 256, 0, stream>>>(W_out, Bbf);
    k_gemm<<<dim3(NB * NN / 128, NV / 128), 256, 0, stream>>>(Abf, Bbf, b_out, out);
}

// Round 7
// 765.688 us; speedup vs baseline: 1.5617x; 1.0686x over previous
//
#include <hip/hip_runtime.h>
#include <hip/hip_bf16.h>

typedef unsigned short u16;
typedef unsigned int u32;
typedef unsigned long long u64;
typedef __attribute__((ext_vector_type(8))) short short8;
typedef __attribute__((ext_vector_type(4))) float f32x4;

#define NB 32      // trees
#define NN 128     // nodes per tree
#define HH 300     // hidden
#define G4 1200    // 4*H
#define NV 32000   // vocab
#define INW 350    // RD+E
#define KP 320     // padded K for MFMA (300 -> 320); also hb16 row stride

// scan decomposition
#define NSLICE 25  // 25 slices x 12 units
#define UPS 12     // hidden units per slice -> 48 gate rows
#define NREP 20    // replicas; chunk q owned by replica q%NREP
#define TPB 192    // 48 rows x 4 col-chunks
#define GMAX 16    // chunk size / max node batch
#define NCHUNK 256 // 4096/16

#define A_LD(p)     __hip_atomic_load((p), __ATOMIC_RELAXED, __HIP_MEMORY_SCOPE_AGENT)
#define A_ST(p, v)  __hip_atomic_store((p), (v), __ATOMIC_RELAXED, __HIP_MEMORY_SCOPE_AGENT)
#define A_ADD(p, v) __hip_atomic_fetch_add((p), (v), __ATOMIC_RELAXED, __HIP_MEMORY_SCOPE_AGENT)

__device__ __forceinline__ float sigm(float x) { return 1.f / (1.f + __expf(-x)); }
__device__ __forceinline__ float tanh_f(float x) {
    float e = __expf(2.f * x);
    return 1.f - 2.f / (e + 1.f);
}
__device__ __forceinline__ float bf2f(u16 v) {
    u32 u = ((u32)v) << 16;
    return __uint_as_float(u);
}
__device__ __forceinline__ u16 f2bf(float f) {
    __hip_bfloat16 b = __float2bfloat16(f);
    return *reinterpret_cast<u16*>(&b);
}

// hb16 layout: [B][129][320] bf16 (slot 0 = root h); c_buf: [B][129][300] f32
__global__ void k_init(const float* __restrict__ rh, u16* __restrict__ hb16,
                       float* __restrict__ c_buf) {
    const int stride = gridDim.x * blockDim.x;
    const int idx = blockIdx.x * blockDim.x + threadIdx.x;
    // zero pad cols 300..319 of all rows (GEMM K-padding)
    for (int e = idx; e < NB * 129 * 20; e += stride) {
        int row = e / 20, c = 300 + (e - row * 20);
        hb16[(size_t)row * KP + c] = 0;
    }
    for (int e = idx; e < NB * HH; e += stride) {
        int b = e / HH, u = e - b * HH;
        float v = rh[e];
        hb16[(size_t)(b * 129) * KP + u] = f2bf(v);
        c_buf[(size_t)(b * 129) * HH + u] = v;
    }
}

// WihT [350][1200]; Wpack[slice][i<75][t<192] = W_hh[row(slice,t)][(t/48)*75+i]
// row(s,t) = 300*(rl/12) + 12*s + rl%12, rl = t%48
__global__ void k_pack(const float* __restrict__ W_ih, const float* __restrict__ W_hh,
                       float* __restrict__ WihT, float* __restrict__ Wpack) {
    const int tot = INW * G4 + NSLICE * 75 * TPB;
    for (int n = blockIdx.x * blockDim.x + threadIdx.x; n < tot; n += gridDim.x * blockDim.x) {
        if (n < INW * G4) {
            int c = n / G4, r = n - c * G4;
            WihT[n] = W_ih[r * INW + c];
        } else {
            int m = n - INW * G4;
            int s = m / (75 * TPB);
            int rem = m - s * (75 * TPB);
            int i = rem / TPB, t = rem - i * TPB;
            int rl = t % 48, cc = t / 48;
            int row = 300 * (rl / UPS) + UPS * s + (rl % UPS);
            int col = cc * 75 + i;
            Wpack[m] = W_hh[row * HH + col];
        }
    }
}

// xg[node][1200] = concat(rel_emb[rel], emb[word]) @ W_ih^T + b_ih
__global__ __launch_bounds__(256) void k_xg(const int* __restrict__ relations,
                                            const int* __restrict__ prev_words,
                                            const float* __restrict__ rel_emb,
                                            const float* __restrict__ emb,
                                            const float* __restrict__ WihT,
                                            const float* __restrict__ b_ih,
                                            float* __restrict__ xg) {
    __shared__ float xl[8][INW];
    __shared__ int rid[8], wid[8];
    const int tid = threadIdx.x;
    const int nb = blockIdx.x * 8;
    if (tid < 8) { rid[tid] = relations[nb + tid]; wid[tid] = prev_words[nb + tid]; }
    __syncthreads();
    for (int idx = tid; idx < 8 * INW; idx += 256) {
        int g = idx / INW, c = idx - g * INW;
        xl[g][c] = (c < 50) ? rel_emb[rid[g] * 50 + c] : emb[wid[g] * HH + (c - 50)];
    }
    __syncthreads();
    for (int k = 0; k < 5; ++k) {
        int r = k * 256 + tid;
        if (r >= G4) break;
        float acc[8] = {0.f, 0.f, 0.f, 0.f, 0.f, 0.f, 0.f, 0.f};
        for (int c = 0; c < INW; ++c) {
            float wv = WihT[(size_t)c * G4 + r];
#pragma unroll
            for (int g = 0; g < 8; ++g) acc[g] += wv * xl[g][c];
        }
        float bi = b_ih[r];
#pragma unroll
        for (int g = 0; g < 8; ++g) xg[(size_t)(nb + g) * G4 + r] = acc[g] + bi;
    }
}

// Build child adjacency, reset queue/done, enqueue roots. Deterministic per launch.
__global__ __launch_bounds__(1024) void k_prep(const int* __restrict__ parents,
                                               int* __restrict__ ready,
                                               int* __restrict__ qtail,
                                               int* __restrict__ kstart,
                                               int* __restrict__ kids,
                                               int* __restrict__ done) {
    __shared__ int cnt_s[4096];
    __shared__ int pfx_s[4096];
    __shared__ int part_s[64];
    __shared__ int rc_s;
    const int tid = threadIdx.x;
    for (int n = tid; n < NB * NN; n += 1024) { cnt_s[n] = 0; ready[n] = -1; done[n] = 0; }
    if (tid == 0) rc_s = 0;
    __syncthreads();
    for (int n = tid; n < NB * NN; n += 1024) {
        int p = parents[n];
        if (p >= 0) atomicAdd(&cnt_s[(n & ~127) + p], 1);
    }
    __syncthreads();
    if (tid < 64) {
        int s = 0;
        for (int k = 0; k < 64; ++k) { int t = cnt_s[tid * 64 + k]; pfx_s[tid * 64 + k] = s; s += t; }
        part_s[tid] = s;
    }
    __syncthreads();
    if (tid == 0) {
        int s = 0;
        for (int k = 0; k < 64; ++k) { int t = part_s[k]; part_s[k] = s; s += t; }
        kstart[4096] = s;
    }
    __syncthreads();
    if (tid < 64) {
        int off = part_s[tid];
        for (int k = 0; k < 64; ++k) pfx_s[tid * 64 + k] += off;
    }
    __syncthreads();
    for (int n = tid; n < NB * NN; n += 1024) kstart[n] = pfx_s[n];
    __syncthreads();
    for (int n = tid; n < NB * NN; n += 1024) {
        int p = parents[n];
        if (p >= 0) {
            int pos = atomicAdd(&pfx_s[(n & ~127) + p], 1);
            kids[pos] = n;
        } else {
            int slot = atomicAdd(&rc_s, 1);
            ready[slot] = n;
        }
    }
    __syncthreads();
    if (tid == 0) qtail[0] = rc_s;
}

// MV + cell for one batch of G nodes, one 12-unit slice. W in VGPRs; ph broadcast
// reads from LDS; cell computes 2-unit pairs and publishes via u32/u64 atomics.
template <int G>
__device__ __forceinline__ void mv_cell(const float (&w)[75], int t, int rl, int cc, int slice,
                                        const int* __restrict__ nid_s,
                                        const float* __restrict__ xg,
                                        const float* __restrict__ b_hh,
                                        u16* __restrict__ hb16,
                                        float* __restrict__ c_buf,
                                        const float* __restrict__ ph,
                                        float* __restrict__ pr,
                                        const float* __restrict__ pcl) {
    float acc[G];
#pragma unroll
    for (int j = 0; j < G; ++j) acc[j] = 0.f;
    const int cb = cc * 75;
#pragma unroll 5
    for (int i = 0; i < 75; ++i) {
        const float wv = w[i];
        const float* pp = &ph[(cb + i) * GMAX];
        if constexpr (G >= 4) {
#pragma unroll
            for (int j4 = 0; j4 < G; j4 += 4) {
                f32x4 a = *(const f32x4*)&pp[j4];
                acc[j4 + 0] = fmaf(wv, a[0], acc[j4 + 0]);
                acc[j4 + 1] = fmaf(wv, a[1], acc[j4 + 1]);
                acc[j4 + 2] = fmaf(wv, a[2], acc[j4 + 2]);
                acc[j4 + 3] = fmaf(wv, a[3], acc[j4 + 3]);
            }
        } else {
#pragma unroll
            for (int j = 0; j < G; ++j) acc[j] = fmaf(wv, pp[j], acc[j]);
        }
    }
    // partials: pr[j][cc*48+rl]
#pragma unroll
    for (int j = 0; j < G; ++j) pr[j * TPB + cc * 48 + rl] = acc[j];
    __syncthreads();
    // cell: thread t < 6*G handles (node j, unit pair up)
    if (t < 6 * G) {
        const int j = t / 6, up = t - j * 6;
        const int ul0 = up * 2;
        const int n = nid_s[j];
        const int b = n >> 7, i = n & 127;
        const int u0 = slice * UPS + ul0;
        const float* pj = pr + j * TPB;
        const float* xgp = xg + (size_t)n * G4;
        float cv[2], hv[2];
#pragma unroll
        for (int un = 0; un < 2; ++un) {
            const int ul = ul0 + un, u = u0 + un;
            float gs[4];
#pragma unroll
            for (int g = 0; g < 4; ++g) {
                const int rr = g * UPS + ul;
                float sum = pj[rr] + pj[48 + rr] + pj[96 + rr] + pj[144 + rr];
                gs[g] = sum + xgp[g * HH + u] + b_hh[g * HH + u];
            }
            const float pc = pcl[j * UPS + ul];
            cv[un] = sigm(gs[1]) * pc + sigm(gs[0]) * tanh_f(gs[2]);
            hv[un] = sigm(gs[3]) * tanh_f(cv[un]);
        }
        const size_t row = (size_t)(b * 129 + i + 1);
        union { float f[2]; u64 v; } cp; cp.f[0] = cv[0]; cp.f[1] = cv[1];
        A_ST((u64*)(c_buf + row * HH + u0), cp.v);
        u32 hp = (u32)f2bf(hv[0]) | ((u32)f2bf(hv[1]) << 16);
        A_ST((u32*)(hb16 + row * KP + u0), hp);
    }
}

// Dataflow scan: 25 slices x 20 replicas = 500 blocks, normal launch.
// Ownership block-cyclic by 16-position chunks; all cross-block h/c traffic via
// relaxed agent-scope atomics (h as bf16x4 u64 words). Producer order:
// __syncthreads (vmcnt0 drain) before done[] adds; 25th add publishes children.
__global__ __launch_bounds__(TPB, 2) void k_scan_slice(const int* __restrict__ parents,
                                                       const float* __restrict__ Wpack,
                                                       const float* __restrict__ xg,
                                                       const float* __restrict__ b_hh,
                                                       u16* __restrict__ hb16,
                                                       float* __restrict__ c_buf,
                                                       int* __restrict__ ready,
                                                       int* __restrict__ qtail,
                                                       int* __restrict__ done,
                                                       const int* __restrict__ kstart,
                                                       const int* __restrict__ kids) {
    __shared__ __align__(16) float ph[HH * GMAX];   // 19.2 KB parent h, [c][j]
    __shared__ float pr[GMAX * TPB];                // 12.3 KB MV partials, [j][cc*48+rl]
    __shared__ float pcl[UPS * GMAX];               // parent c slice, [j*12+ul]
    __shared__ int nid_s[GMAX];
    __shared__ int par_s[GMAX];
    __shared__ int gc_s;

    const int t = threadIdx.x;
    const int rep = blockIdx.x % NREP;
    const int slice = blockIdx.x / NREP;
    const int rl = t % 48, cc = t / 48;

    // register-resident W slice (once per block, coalesced)
    float w[75];
    {
        const float* wp = Wpack + (size_t)slice * 75 * TPB + t;
#pragma unroll
        for (int i = 0; i < 75; ++i) w[i] = wp[i * TPB];
    }

    for (int ch = rep; ch < NCHUNK; ch += NREP) {
        const int base = ch * GMAX;
        int lp = 0;
        while (lp < GMAX) {
            if (t == 0) {
                int v;
                while ((v = A_LD(&ready[base + lp])) < 0) __builtin_amdgcn_s_sleep(2);
                nid_s[0] = v; par_s[0] = parents[v];
                int avail = 1;
                while (lp + avail < GMAX) {
                    int u = A_LD(&ready[base + lp + avail]);
                    if (u < 0) break;
                    nid_s[avail] = u; par_s[avail] = parents[u];
                    ++avail;
                }
                gc_s = (avail >= 16) ? 16 : (avail >= 8) ? 8 : (avail >= 4) ? 4
                                                        : (avail >= 2) ? 2 : 1;
            }
            __syncthreads();
            const int gc = gc_s;
            // stage parent h: u64 atomic loads of 4xbf16, unpack to LDS [c][j]
            for (int e = t; e < 75 * gc; e += TPB) {
                const int j = e / 75, wq = e - j * 75;
                const int n = nid_s[j];
                const u64* hrow = (const u64*)(hb16 +
                    (size_t)((n >> 7) * 129 + par_s[j] + 1) * KP);
                u64 v = A_LD(&hrow[wq]);
                const int c0 = wq * 4;
                ph[(c0 + 0) * GMAX + j] = bf2f((u16)v);
                ph[(c0 + 1) * GMAX + j] = bf2f((u16)(v >> 16));
                ph[(c0 + 2) * GMAX + j] = bf2f((u16)(v >> 32));
                ph[(c0 + 3) * GMAX + j] = bf2f((u16)(v >> 48));
            }
            // stage parent c slice: u64 pair loads
            for (int e = t; e < 6 * gc; e += TPB) {
                const int j = e / 6, pq = e - j * 6;
                const int n = nid_s[j];
                const u64* crow = (const u64*)(c_buf +
                    (size_t)((n >> 7) * 129 + par_s[j] + 1) * HH + slice * UPS);
                u64 v = A_LD(&crow[pq]);
                union { u64 v; float f[2]; } uu; uu.v = v;
                pcl[j * UPS + pq * 2] = uu.f[0];
                pcl[j * UPS + pq * 2 + 1] = uu.f[1];
            }
            __syncthreads();
            switch (gc) {
                case 16: mv_cell<16>(w, t, rl, cc, slice, nid_s, xg, b_hh, hb16, c_buf, ph, pr, pcl); break;
                case 8:  mv_cell<8>(w, t, rl, cc, slice, nid_s, xg, b_hh, hb16, c_buf, ph, pr, pcl); break;
                case 4:  mv_cell<4>(w, t, rl, cc, slice, nid_s, xg, b_hh, hb16, c_buf, ph, pr, pcl); break;
                case 2:  mv_cell<2>(w, t, rl, cc, slice, nid_s, xg, b_hh, hb16, c_buf, ph, pr, pcl); break;
                default: mv_cell<1>(w, t, rl, cc, slice, nid_s, xg, b_hh, hb16, c_buf, ph, pr, pcl); break;
            }
            // barrier drains all threads' h/c atomic stores (vmcnt0) before done adds
            __syncthreads();
            if (t < gc) {
                const int n_mine = nid_s[t];
                const int old = A_ADD(&done[n_mine], 1);
                if (old == NSLICE - 1) {  // all 25 slices done -> children ready
                    const int ks = kstart[n_mine], ke = kstart[n_mine + 1];
                    for (int q = ks; q < ke; ++q) {
                        const int kd = kids[q];
                        const int pos = A_ADD(qtail, 1);
                        A_ST(&ready[pos], kd);
                    }
                }
            }
            lp += gc;
            __syncthreads();  // nid_s reuse safety for next poll
        }
    }
}

// cast W_out -> bf16 [32000][320] (zero-padded K)
__global__ void k_cast_B(const float* __restrict__ W_out, u16* __restrict__ Bm) {
    for (int e = blockIdx.x * blockDim.x + threadIdx.x; e < NV * KP;
         e += gridDim.x * blockDim.x) {
        int v = e / KP, k = e - v * KP;
        float x = (k < HH) ? W_out[v * HH + k] : 0.f;
        Bm[e] = f2bf(x);
    }
}

// logits[4096][32000] = A(bf16, from hb16) @ B(bf16)^T + b_out, fp32 accum.
// A row r of tile mblk lives at hb16 row mblk*129 + 1 + r (slot-0 root rows skipped).
__global__ __launch_bounds__(256) void k_gemm(const u16* __restrict__ hb16,
                                              const u16* __restrict__ Bbf,
                                              const float* __restrict__ b_out,
                                              float* __restrict__ out) {
    __shared__ __align__(16) u16 As[128 * 40];
    __shared__ __align__(16) u16 Bs[128 * 40];
    const int tid = threadIdx.x;
    const int lane = tid & 63, wv = tid >> 6;
    const int wm = wv >> 1, wn = wv & 1;
    const int mblk = blockIdx.x, nblk = blockIdx.y;
    const u16* Ag = hb16 + ((size_t)mblk * 129 + 1) * KP;
    const u16* Bg = Bbf + (size_t)nblk * 128 * KP;
    f32x4 acc[4][4] = {};
    const int lrow = lane & 15, lseg = lane >> 4;
    for (int kk = 0; kk < KP; kk += 32) {
#pragma unroll
        for (int q = 0; q < 2; ++q) {
            int s = tid + q * 256;
            int r = s >> 2, seg = s & 3;
            *(uint4*)&As[r * 40 + seg * 8] = *(const uint4*)&Ag[r * KP + kk + seg * 8];
            *(uint4*)&Bs[r * 40 + seg * 8] = *(const uint4*)&Bg[r * KP + kk + seg * 8];
        }
        __syncthreads();
        short8 av[4], bv[4];
#pragma unroll
        for (int i = 0; i < 4; ++i) {
            av[i] = *(const short8*)&As[(wm * 64 + i * 16 + lrow) * 40 + lseg * 8];
            bv[i] = *(const short8*)&Bs[(wn * 64 + i * 16 + lrow) * 40 + lseg * 8];
        }
#pragma unroll
        for (int i = 0; i < 4; ++i)
#pragma unroll
            for (int j = 0; j < 4; ++j)
                acc[i][j] = __builtin_amdgcn_mfma_f32_16x16x32_bf16(av[i], bv[j], acc[i][j],
                                                                    0, 0, 0);
        __syncthreads();
    }
#pragma unroll
    for (int j = 0; j < 4; ++j) {
        int col = nblk * 128 + wn * 64 + j * 16 + lrow;
        float bo = b_out[col];
#pragma unroll
        for (int i = 0; i < 4; ++i) {
            int row0 = mblk * 128 + wm * 64 + i * 16 + lseg * 4;
#pragma unroll
            for (int q = 0; q < 4; ++q) {
                out[(size_t)(row0 + q) * NV + col] = acc[i][j][q] + bo;
            }
        }
    }
}

extern "C" void kernel_launch(void* const* d_in, const int* in_sizes, int n_in,
                              void* d_out, int out_size, void* d_ws, size_t ws_size,
                              hipStream_t stream) {
    const float* root_hidden = (const float*)d_in[0];
    const int* relations = (const int*)d_in[1];
    const int* prev_words = (const int*)d_in[2];
    const int* parents = (const int*)d_in[3];
    const float* emb = (const float*)d_in[4];
    const float* rel_emb = (const float*)d_in[5];
    const float* W_ih = (const float*)d_in[6];
    const float* W_hh = (const float*)d_in[7];
    const float* b_ih = (const float*)d_in[8];
    const float* b_hh = (const float*)d_in[9];
    const float* W_out = (const float*)d_in[10];
    const float* b_out = (const float*)d_in[11];
    float* out = (float*)d_out;

    float* WihT = (float*)d_ws;                  // 420000 f32
    float* Wpack = WihT + 420000;                // 360000 f32
    float* xg = Wpack + 360000;                  // 4915200 f32
    float* c_buf = xg + 4915200;                 // 1238400 f32
    u16* hb16 = (u16*)(c_buf + 1238400);         // 32*129*320 = 1320960 u16
    u16* Bbf = hb16 + 1320960;                   // 10240000 u16
    int* ready = (int*)(Bbf + 10240000);         // 4096 i32
    int* qtail = ready + 4096;                   // 16 i32
    int* kstart = qtail + 16;                    // 4097 i32
    int* kids = kstart + 4097;                   // 4096 i32 (+pad)
    int* done = kids + 4112;                     // 4096 i32

    k_init<<<128, 256, 0, stream>>>(root_hidden, hb16, c_buf);
    k_pack<<<2048, 256, 0, stream>>>(W_ih, W_hh, WihT, Wpack);
    k_xg<<<NB * NN / 8, 256, 0, stream>>>(relations, prev_words, rel_emb, emb, WihT, b_ih, xg);
    k_prep<<<1, 1024, 0, stream>>>(parents, ready, qtail, kstart, kids, done);

    k_scan_slice<<<dim3(NSLICE * NREP), dim3(TPB), 0, stream>>>(
        parents, Wpack, xg, b_hh, hb16, c_buf, ready, qtail, done, kstart, kids);

    k_cast_B<<<4096, 256, 0, stream>>>(W_out, Bbf);
    k_gemm<<<dim3(NB * NN / 128, NV / 128), 256, 0, stream>>>(hb16, Bbf, b_out, out);
}